// Round 16
// baseline (359.523 us; speedup 1.0000x reference)
//
#include <hip/hip_runtime.h>

typedef unsigned short u16;
typedef __attribute__((ext_vector_type(8))) short s8v;       // 8 bf16 MFMA frag
typedef __attribute__((ext_vector_type(4))) float f4v;       // MFMA acc
typedef __attribute__((ext_vector_type(8))) unsigned short u16x8;
typedef __attribute__((ext_vector_type(4))) unsigned short u16x4;

__device__ __forceinline__ float b2f(u16 u) {
  unsigned int v = ((unsigned int)u) << 16;
  float f;
  __builtin_memcpy(&f, &v, 4);
  return f;
}
__device__ __forceinline__ u16 f2b(float f) {  // RNE f32 -> bf16
  unsigned int v;
  __builtin_memcpy(&v, &f, 4);
  v = v + 0x7fffu + ((v >> 16) & 1u);
  return (u16)(v >> 16);
}
__device__ __forceinline__ void gl_lds16(const void* g, void* l) {
  __builtin_amdgcn_global_load_lds((__attribute__((address_space(1))) void*)g,
                                   (__attribute__((address_space(3))) void*)l,
                                   16, 0, 0);
}
__device__ __forceinline__ f4v mfma16(s8v a, s8v b, f4v c) {
  return __builtin_amdgcn_mfma_f32_16x16x32_bf16(a, b, c, 0, 0, 0);
}

// ---------------- K0: f32 -> bf16 for x, Wq, Wk, Wv, Wo; proj pre-scaled 1/8
__global__ __launch_bounds__(256) void k_convert(
    const float* __restrict__ x, const float* __restrict__ wq,
    const float* __restrict__ wk, const float* __restrict__ wv,
    const float* __restrict__ wo, const float* __restrict__ proj,
    u16* __restrict__ xb, u16* __restrict__ wqb, u16* __restrict__ wkb,
    u16* __restrict__ wvb, u16* __restrict__ wob, u16* __restrict__ projb) {
  const int NX = 4194304, NW = 262144, NP = 65536;  // vec4 counts
  const int total = NX + 4 * NW + NP;
  for (int i = blockIdx.x * 256 + threadIdx.x; i < total; i += gridDim.x * 256) {
    const float* src;
    u16* dst;
    int off;
    float scale = 1.0f;
    if (i < NX) { src = x; dst = xb; off = i; }
    else if (i < NX + NW) { src = wq; dst = wqb; off = i - NX; }
    else if (i < NX + 2 * NW) { src = wk; dst = wkb; off = i - NX - NW; }
    else if (i < NX + 3 * NW) { src = wv; dst = wvb; off = i - NX - 2 * NW; }
    else if (i < NX + 4 * NW) { src = wo; dst = wob; off = i - NX - 3 * NW; }
    else { src = proj; dst = projb; off = i - NX - 4 * NW; scale = 0.125f; }
    const float4 v = reinterpret_cast<const float4*>(src)[off];
    u16x4 o;
    o[0] = f2b(v.x * scale); o[1] = f2b(v.y * scale);
    o[2] = f2b(v.z * scale); o[3] = f2b(v.w * scale);
    reinterpret_cast<u16x4*>(dst)[off] = o;
  }
}

// ---------------- pure-bf16 128x128 BT-GEMM, XCD-chunked flat grid.
// BK=64, chunk-XOR LDS swizzle; K fixed 1024. Both epilogues LDS-bounced.
// (r11/r14, verified)
template <int COUTF32, int NCB>
__global__ __launch_bounds__(256) void k_gemm_swz(
    const u16* __restrict__ A, const u16* __restrict__ W,
    void* __restrict__ Cq, void* __restrict__ Ck, void* __restrict__ Cv,
    const float* __restrict__ bias) {
  const int bid = blockIdx.x;
  const int xcd = bid & 7, slot = bid >> 3;
  const int yg = slot / NCB, cb = slot - yg * NCB;
  const long row0 = (long)(yg * 8 + xcd) * 128;
  const int wrow0 = cb * 128;
  void* C = (cb < 8) ? Cq : (cb < 16) ? Ck : Cv;
  const int col0 = (cb & 7) * 128;
  __shared__ u16 As[128 * 64];
  __shared__ u16 Bs[128 * 64];
  const int tid = threadIdx.x, w = tid >> 6, l = tid & 63;
  const int wr = w >> 1, wc = w & 1, fr = l & 15, fq = l >> 4;
  f4v acc[4][4];
#pragma unroll
  for (int i = 0; i < 4; ++i)
#pragma unroll
    for (int j = 0; j < 4; ++j) acc[i][j] = 0.f;
  const int lr = l >> 3, lc = l & 7;  // staging: lane row-part / chunk
  for (int kt = 0; kt < 16; ++kt) {
    const int k0 = kt << 6;
    __syncthreads();  // prev compute done -> LDS rewrite safe
#pragma unroll
    for (int q = 0; q < 4; ++q) {
      const int r = q * 32 + w * 8 + lr;         // tile row this lane stages
      const int sc = (lc ^ (r & 7)) << 3;        // swizzled source chunk
      gl_lds16(A + (row0 + r) * 1024L + k0 + sc, (char*)As + q * 4096 + w * 1024);
      gl_lds16(W + (wrow0 + r) * 1024L + k0 + sc, (char*)Bs + q * 4096 + w * 1024);
    }
    __syncthreads();  // staged data visible
#pragma unroll
    for (int ks = 0; ks < 2; ++ks) {
      s8v af[4], bf[4];
#pragma unroll
      for (int i = 0; i < 4; ++i) {
        const int R = wr * 64 + i * 16 + fr;
        af[i] = *(const s8v*)&As[R * 64 + (((ks * 4 + fq) ^ (R & 7)) << 3)];
      }
#pragma unroll
      for (int j = 0; j < 4; ++j) {
        const int R = wc * 64 + j * 16 + fr;
        bf[j] = *(const s8v*)&Bs[R * 64 + (((ks * 4 + fq) ^ (R & 7)) << 3)];
      }
#pragma unroll
      for (int i = 0; i < 4; ++i)
#pragma unroll
        for (int j = 0; j < 4; ++j) acc[i][j] = mfma16(af[i], bf[j], acc[i][j]);
    }
  }
  __syncthreads();  // all MFMA ds_reads of As/Bs done -> epilogue reuse safe
  if (COUTF32) {
    // per-wave f32 LDS bounce -> 4x float4 stores/lane (256B row segments)
    float* myl = (float*)((w < 4) ? ((char*)As + w * 4096)
                                  : ((char*)Bs + (w - 4) * 4096));
    const int rr2 = l >> 2, c2 = (l & 3) * 16;
    float bv[4];
#pragma unroll
    for (int j = 0; j < 4; ++j)
      bv[j] = bias ? bias[col0 + wc * 64 + j * 16 + fr] : 0.f;
#pragma unroll
    for (int i = 0; i < 4; ++i) {
#pragma unroll
      for (int j = 0; j < 4; ++j)
#pragma unroll
        for (int r = 0; r < 4; ++r)
          myl[(fq * 4 + r) * 64 + j * 16 + fr] = acc[i][j][r] + bv[j];
      float* dst = (float*)C + (row0 + wr * 64 + i * 16 + rr2) * 1024L +
                   col0 + wc * 64 + c2;
#pragma unroll
      for (int k = 0; k < 4; ++k)
        *(float4*)(dst + k * 4) = *(const float4*)&myl[rr2 * 64 + c2 + k * 4];
    }
  } else {
    // per-wave bf16 LDS bounce -> u16x8 stores (r10, verified)
    u16* myl = As + w * 1024;  // 2 KB per wave (16 x 64 u16)
    const int rr2 = l >> 2, c2 = (l & 3) * 16;
#pragma unroll
    for (int i = 0; i < 4; ++i) {
#pragma unroll
      for (int j = 0; j < 4; ++j)
#pragma unroll
        for (int r = 0; r < 4; ++r)
          myl[(fq * 4 + r) * 64 + j * 16 + fr] = f2b(acc[i][j][r]);
      const u16x8 o0 = *(const u16x8*)&myl[rr2 * 64 + c2];
      const u16x8 o1 = *(const u16x8*)&myl[rr2 * 64 + c2 + 8];
      u16* dst = (u16*)C + (row0 + wr * 64 + i * 16 + rr2) * 1024L + col0 + wc * 64 + c2;
      *(u16x8*)dst = o0;
      *(u16x8*)(dst + 8) = o1;
    }
  }
}

// ---------------- K2: fused phiK + split-K KV partials + f32 ksum ----------
// 8 waves, 128-t chunks, T14 async-stage, in-register norms. ALL LDS buffers
// power-of-2 stride + chunk-XOR swizzle (r11-validated pattern).
// grid (4 chunks of 1024 t, 64 bh).
__global__ __launch_bounds__(512) void k_kvfused(
    const u16* __restrict__ Kb, const u16* __restrict__ Vb,
    const u16* __restrict__ projb, float* __restrict__ kvp,
    float* __restrict__ ksp) {
  __shared__ u16 Ps[256 * 64];     // proj head [m][dk] swz    32 KB
  __shared__ u16 PhiT[256 * 128];  // [m][t'] swz              64 KB
  __shared__ u16 Ks[128 * 64];     // K subtile [t'][dk] swz   16 KB
  __shared__ u16 VT[64 * 128];     // V^T [e][t'] swz          16 KB
  const int tid = threadIdx.x, w = tid >> 6, l = tid & 63;
  const int fr = l & 15, fq = l >> 4;
  const int c = blockIdx.x, bh = blockIdx.y, b = bh >> 4, h = bh & 15;
#pragma unroll
  for (int q = 0; q < 4; ++q) {
    const int flat = q * 4096 + tid * 8;
    const int m = flat >> 6, cc = flat & 63;
    *(u16x8*)&Ps[m * 64 + (((cc >> 3) ^ (m & 7)) << 3)] =
        *(const u16x8*)&projb[h * 16384 + flat];
  }
  f4v kacc[2][4];
  float ksum = 0.f;
  const int km = tid & 255, kh = tid >> 8;  // ksum: m, t-half
#pragma unroll
  for (int i = 0; i < 2; ++i)
#pragma unroll
    for (int j = 0; j < 4; ++j) kacc[i][j] = 0.f;
  // staging coords
  const int kr = tid >> 3, kc = tid & 7;                // K: row-part, chunk
  const int vt = tid >> 2, ve0 = (tid & 3) * 16;        // V: t, e-base
  const long kbase = (long)b * 4096 + (long)c * 1024;
  // prologue: loads for it=0
  u16x8 ck0 = *(const u16x8*)&Kb[(kbase + kr) * 1024 + h * 64 + kc * 8];
  u16x8 ck1 = *(const u16x8*)&Kb[(kbase + 64 + kr) * 1024 + h * 64 + kc * 8];
  u16x8 cv0 = *(const u16x8*)&Vb[(kbase + vt) * 1024 + h * 64 + ve0];
  u16x8 cv1 = *(const u16x8*)&Vb[(kbase + vt) * 1024 + h * 64 + ve0 + 8];
  for (int it = 0; it < 8; ++it) {
    __syncthreads();  // A: prev iter's PhiT/VT/Ks reads done -> rewrite safe
    *(u16x8*)&Ks[kr * 64 + ((kc ^ (kr & 7)) << 3)] = ck0;
    *(u16x8*)&Ks[(64 + kr) * 64 + ((kc ^ (kr & 7)) << 3)] = ck1;
#pragma unroll
    for (int jj = 0; jj < 8; ++jj) {
      const int e = ve0 + jj;
      VT[e * 128 + (((vt >> 3) ^ (e & 7)) << 3) + (vt & 7)] = cv0[jj];
    }
#pragma unroll
    for (int jj = 0; jj < 8; ++jj) {
      const int e = ve0 + 8 + jj;
      VT[e * 128 + (((vt >> 3) ^ (e & 7)) << 3) + (vt & 7)] = cv1[jj];
    }
    __syncthreads();  // B: Ks / VT staged
    if (it < 7) {  // T14: issue next iter's loads under this iter's compute
      const long t0n = kbase + (it + 1) * 128;
      ck0 = *(const u16x8*)&Kb[(t0n + kr) * 1024 + h * 64 + kc * 8];
      ck1 = *(const u16x8*)&Kb[(t0n + 64 + kr) * 1024 + h * 64 + kc * 8];
      cv0 = *(const u16x8*)&Vb[(t0n + vt) * 1024 + h * 64 + ve0];
      cv1 = *(const u16x8*)&Vb[(t0n + vt) * 1024 + h * 64 + ve0 + 8];
    }
    float nrm;
    {  // in-register norms for row = w*16 + (l>>2) (intra-wave)
      const int row = w * 16 + (l >> 2), part = l & 3;
      const u16x8 a0 = *(const u16x8*)&Ks[row * 64 + (((part * 2) ^ (row & 7)) << 3)];
      const u16x8 a1 = *(const u16x8*)&Ks[row * 64 + (((part * 2 + 1) ^ (row & 7)) << 3)];
      float s = 0.f;
#pragma unroll
      for (int jj = 0; jj < 8; ++jj) { const float v = b2f(a0[jj]); s += v * v; }
#pragma unroll
      for (int jj = 0; jj < 8; ++jj) { const float v = b2f(a1[jj]); s += v * v; }
      s += __shfl_xor(s, 1);
      s += __shfl_xor(s, 2);
      nrm = s * 0.015625f;  // ||k/8||^2
    }
    f4v pacc[16];
#pragma unroll
    for (int f = 0; f < 16; ++f) pacc[f] = 0.f;
#pragma unroll
    for (int ks = 0; ks < 2; ++ks) {
      const int ar = w * 16 + fr;
      const s8v a = *(const s8v*)&Ks[ar * 64 + (((ks * 4 + fq) ^ (ar & 7)) << 3)];
#pragma unroll
      for (int f = 0; f < 16; ++f) {
        const int br = f * 16 + fr;
        const s8v bb = *(const s8v*)&Ps[br * 64 + (((ks * 4 + fq) ^ (br & 7)) << 3)];
        pacc[f] = mfma16(a, bb, pacc[f]);
      }
    }
    float mx[4] = {-3.4e38f, -3.4e38f, -3.4e38f, -3.4e38f};
#pragma unroll
    for (int f = 0; f < 16; ++f)
#pragma unroll
      for (int r = 0; r < 4; ++r) mx[r] = fmaxf(mx[r], pacc[f][r]);
#pragma unroll
    for (int sft = 1; sft < 16; sft <<= 1)
#pragma unroll
      for (int r = 0; r < 4; ++r) mx[r] = fmaxf(mx[r], __shfl_xor(mx[r], sft));
    float nsq[4];
#pragma unroll
    for (int r = 0; r < 4; ++r) nsq[r] = __shfl(nrm, (fq * 4 + r) * 4);
#pragma unroll
    for (int f = 0; f < 16; ++f) {
      u16x4 o;
#pragma unroll
      for (int r = 0; r < 4; ++r)
        o[r] = f2b((__expf(pacc[f][r] - mx[r] - 0.5f * nsq[r]) + 1e-6f) * 0.0625f);
      const int mrow = f * 16 + fr;
      *(u16x4*)&PhiT[mrow * 128 + (((w * 2 + (fq >> 1)) ^ (mrow & 7)) << 3) +
                     (fq & 1) * 4] = o;
    }
    __syncthreads();  // D: PhiT visible (VT staged since B)
#pragma unroll
    for (int ks = 0; ks < 4; ++ks) {
      s8v af[2], bf[4];
#pragma unroll
      for (int i = 0; i < 2; ++i) {
        const int ar = w * 32 + i * 16 + fr;
        af[i] = *(const s8v*)&PhiT[ar * 128 + (((ks * 4 + fq) ^ (ar & 7)) << 3)];
      }
#pragma unroll
      for (int j = 0; j < 4; ++j) {
        const int br = j * 16 + fr;
        bf[j] = *(const s8v*)&VT[br * 128 + (((ks * 4 + fq) ^ (br & 7)) << 3)];
      }
#pragma unroll
      for (int i = 0; i < 2; ++i)
#pragma unroll
        for (int j = 0; j < 4; ++j) kacc[i][j] = mfma16(af[i], bf[j], kacc[i][j]);
    }
    // distributed f32 ksum: thread owns (m = tid&255, t-half = tid>>8)
#pragma unroll
    for (int t8 = 0; t8 < 8; ++t8) {
      const u16x8 p =
          *(const u16x8*)&PhiT[km * 128 + (((kh * 8 + t8) ^ (km & 7)) << 3)];
#pragma unroll
      for (int jj = 0; jj < 8; ++jj) ksum += b2f(p[jj]);
    }
  }
  const long obase = (long)(c * 64 + bh) * 16384;
#pragma unroll
  for (int i = 0; i < 2; ++i) {
    const int m = w * 32 + i * 16 + fq * 4;
#pragma unroll
    for (int j = 0; j < 4; ++j)
#pragma unroll
      for (int r = 0; r < 4; ++r)
        kvp[obase + (long)(m + r) * 64 + j * 16 + fr] = kacc[i][j][r];
  }
  ksp[(long)(c * 64 + bh) * 512 + tid] = ksum;
}

// ---------------- K3: reduce 4 split-K partials -> KVT bf16 [bh][e][m], f32 Ksum
__global__ __launch_bounds__(256) void k_red(
    const float* __restrict__ kvp, const float* __restrict__ ksp,
    u16* __restrict__ KVT, float* __restrict__ ksumf) {
  const int bh = blockIdx.x, qq = blockIdx.y, tid = threadIdx.x;
  for (int it = 0; it < 16; ++it) {
    const int idx = (qq * 16 + it) * 256 + tid;
    const int m = idx >> 6, e = idx & 63;
    float s = 0.f;
#pragma unroll
    for (int cc = 0; cc < 4; ++cc)
      s += kvp[(long)(cc * 64 + bh) * 16384 + (long)m * 64 + e];
    KVT[(long)bh * 16384 + (long)e * 256 + m] = f2b(s);
  }
  if (qq == 0) {
    float s = 0.f;
#pragma unroll
    for (int cc = 0; cc < 4; ++cc)
      s += ksp[(long)(cc * 64 + bh) * 512 + tid] +
           ksp[(long)(cc * 64 + bh) * 512 + 256 + tid];
    ksumf[bh * 256 + tid] = s;
  }
}

// ---------------- K4: wave-independent fused phiQ + num + den -> merged -----
// 8 waves, ONE barrier; all LDS power-of-2 stride + chunk-XOR swizzle.
// grid (4 t-quarters, 64 bh).
__global__ __launch_bounds__(512) void k_numfused(
    const u16* __restrict__ Qb, const u16* __restrict__ projb,
    const u16* __restrict__ KVT, const float* __restrict__ ksumf,
    u16* __restrict__ merged) {
  __shared__ u16 Ps[256 * 64];       // proj head swz       32 KB
  __shared__ u16 Bs[64 * 256];       // KVT[e][m] swz       32 KB
  __shared__ u16 PhiW[8][16 * 256];  // per-wave swz        64 KB
  __shared__ float ksl[256];
  const int tid = threadIdx.x, w = tid >> 6, l = tid & 63;
  const int fr = l & 15, fq = l >> 4;
  const int tq = blockIdx.x, bh = blockIdx.y, b = bh >> 4, h = bh & 15;
#pragma unroll
  for (int q = 0; q < 4; ++q) {
    const int flat = q * 4096 + tid * 8;
    const int m = flat >> 6, cc = flat & 63;
    *(u16x8*)&Ps[m * 64 + (((cc >> 3) ^ (m & 7)) << 3)] =
        *(const u16x8*)&projb[h * 16384 + flat];
  }
  {
    const int e = tid >> 3, c8 = (tid & 7) * 4;
#pragma unroll
    for (int k = 0; k < 4; ++k)
      *(u16x8*)&Bs[e * 256 + (((c8 + k) ^ (e & 7)) << 3)] =
          *(const u16x8*)&KVT[(long)bh * 16384 + e * 256 + (c8 + k) * 8];
  }
  if (tid < 256) ksl[tid] = ksumf[bh * 256 + tid];
  u16* Pw = &PhiW[w][0];
  const long tbase = (long)b * 4096 + tq * 1024 + w * 128;  // wave's t range
  const u16* qrow = Qb + (tbase + fr) * 1024 + h * 64 + fq * 8;
  s8v a0 = *(const s8v*)&qrow[0];
  s8v a1 = *(const s8v*)&qrow[32];
  __syncthreads();  // Ps / Bs / ksl staged (single barrier in kernel)
  for (int n = 0; n < 8; ++n) {
    s8v n0, n1;
    if (n < 7) {  // prefetch next tile's Q frags
      n0 = *(const s8v*)&qrow[(long)(n + 1) * 16 * 1024];
      n1 = *(const s8v*)&qrow[(long)(n + 1) * 16 * 1024 + 32];
    }
    // ||q/8||^2 for row fr of this tile (in-register, intra-wave)
    float s = 0.f;
#pragma unroll
    for (int jj = 0; jj < 8; ++jj) { const float v = b2f((u16)a0[jj]); s += v * v; }
#pragma unroll
    for (int jj = 0; jj < 8; ++jj) { const float v = b2f((u16)a1[jj]); s += v * v; }
    s += __shfl_xor(s, 16);
    s += __shfl_xor(s, 32);
    s *= 0.015625f;
    f4v pacc[16];
#pragma unroll
    for (int f = 0; f < 16; ++f) pacc[f] = 0.f;
#pragma unroll
    for (int f = 0; f < 16; ++f) {
      const int br = f * 16 + fr;
      pacc[f] = mfma16(a0, *(const s8v*)&Ps[br * 64 + ((fq ^ (br & 7)) << 3)], pacc[f]);
    }
#pragma unroll
    for (int f = 0; f < 16; ++f) {
      const int br = f * 16 + fr;
      pacc[f] = mfma16(a1, *(const s8v*)&Ps[br * 64 + (((4 + fq) ^ (br & 7)) << 3)], pacc[f]);
    }
    float mx[4] = {-3.4e38f, -3.4e38f, -3.4e38f, -3.4e38f};
#pragma unroll
    for (int f = 0; f < 16; ++f)
#pragma unroll
      for (int r = 0; r < 4; ++r) mx[r] = fmaxf(mx[r], pacc[f][r]);
#pragma unroll
    for (int sft = 1; sft < 16; sft <<= 1)
#pragma unroll
      for (int r = 0; r < 4; ++r) mx[r] = fmaxf(mx[r], __shfl_xor(mx[r], sft));
    float nsq[4];
#pragma unroll
    for (int r = 0; r < 4; ++r) nsq[r] = __shfl(s, fq * 4 + r);
    float dp[4] = {0.f, 0.f, 0.f, 0.f};
#pragma unroll
    for (int f = 0; f < 16; ++f) {
      const float kv = ksl[f * 16 + fr];
      const int ch = f * 2 + (fr >> 3), wi = fr & 7;
#pragma unroll
      for (int r = 0; r < 4; ++r) {
        const u16 pb = f2b((__expf(pacc[f][r] - mx[r] - 0.5f * nsq[r]) + 1e-6f) * 0.0625f);
        const int row = fq * 4 + r;
        Pw[row * 256 + ((ch ^ (row & 7)) << 3) + wi] = pb;
        dp[r] += b2f(pb) * kv;  // den from the same bf16 phi as num
      }
    }
#pragma unroll
    for (int sft = 1; sft < 16; sft <<= 1)
#pragma unroll
      for (int r = 0; r < 4; ++r) dp[r] += __shfl_xor(dp[r], sft);
    float rd[4];
#pragma unroll
    for (int r = 0; r < 4; ++r) rd[r] = 1.0f / (dp[r] + 1e-6f);
    // num MFMA: A = Pw rows (t_local=fr), B = Bs (KVT[e][m])
    f4v acc[4];
#pragma unroll
    for (int j = 0; j < 4; ++j) acc[j] = 0.f;
#pragma unroll
    for (int kt = 0; kt < 8; ++kt) {
      const s8v af = *(const s8v*)&Pw[fr * 256 + (((kt * 4 + fq) ^ (fr & 7)) << 3)];
#pragma unroll
      for (int j = 0; j < 4; ++j) {
        const int br = j * 16 + fr;
        acc[j] = mfma16(af, *(const s8v*)&Bs[br * 256 + (((kt * 4 + fq) ^ (br & 7)) << 3)], acc[j]);
      }
    }
    // bounce via Pw (phi dead after num MFMA; same-wave DS ordering)
#pragma unroll
    for (int j = 0; j < 4; ++j) {
      const int ch = j * 2 + (fr >> 3), wi = fr & 7;
#pragma unroll
      for (int r = 0; r < 4; ++r) {
        const int row = fq * 4 + r;
        Pw[row * 256 + ((ch ^ (row & 7)) << 3) + wi] = f2b(acc[j][r] * rd[r]);
      }
    }
    {
      const int row = l >> 2;
      const u16x8 o0 = *(const u16x8*)&Pw[row * 256 + ((((l & 3) * 2) ^ (row & 7)) << 3)];
      const u16x8 o1 = *(const u16x8*)&Pw[row * 256 + ((((l & 3) * 2 + 1) ^ (row & 7)) << 3)];
      u16* dst = merged + (tbase + n * 16 + row) * 1024 + h * 64 + (l & 3) * 16;
      *(u16x8*)dst = o0;
      *(u16x8*)(dst + 8) = o1;
    }
    a0 = n0;
    a1 = n1;
  }
}

extern "C" void kernel_launch(void* const* d_in, const int* in_sizes, int n_in,
                              void* d_out, int out_size, void* d_ws, size_t ws_size,
                              hipStream_t stream) {
  const float* x = (const float*)d_in[0];
  const float* Wq = (const float*)d_in[1];
  const float* Wk = (const float*)d_in[2];
  const float* Wv = (const float*)d_in[3];
  const float* Wo = (const float*)d_in[4];
  const float* bo = (const float*)d_in[5];
  const float* proj = (const float*)d_in[6];
  char* ws = (char*)d_ws;
  // V (bf16) lives in the first 33.5 MB of d_out (f32, 67 MB) until the final
  // GEMM overwrites all of d_out with the f32 result.
  u16* Vout = (u16*)d_out;
  // workspace layout — peak ~111.7 MB
  u16* xb = (u16*)(ws + 0L);               // 33.5 MB; dead after QKV GEMM
  u16* wqb = (u16*)(ws + 33554432L);       // 2 MB  | wqb/wkb/wvb contiguous =
  u16* wkb = (u16*)(ws + 35651584L);       // 2 MB  | fused W [3072,1024]
  u16* wvb = (u16*)(ws + 37748736L);       // 2 MB  |
  u16* wob = (u16*)(ws + 39845888L);       // 2 MB; live until final GEMM
  u16* projb = (u16*)(ws + 41943040L);     // 0.5 MB
  u16* Qb = (u16*)(ws + 42467328L);        // 33.5 MB
  u16* Kb = (u16*)(ws + 76021760L);        // 33.5 MB; merged aliases after kvfused
  u16* KVT = (u16*)(ws + 109576192L);      // 2 MB
  float* ksumf = (float*)(ws + 111673344L);// 64 KB
  float* kvp = (float*)xb;                 // alias (xb dead): 16.8 MB
  float* ksp = (float*)(ws + 16777216L);   // alias inside xb: 0.5 MB
  u16* merged = Kb;                        // alias (Kb dead after kvfused)
  (void)in_sizes; (void)n_in; (void)out_size; (void)ws_size;

  k_convert<<<dim3(2048), dim3(256), 0, stream>>>(x, Wq, Wk, Wv, Wo, proj,
                                                  xb, wqb, wkb, wvb, wob, projb);
  // Q,K,V = x @ [Wq;Wk;Wv]^T  (fused W, XCD-chunked flat grid: 128*24 blocks)
  k_gemm_swz<0, 24><<<dim3(3072), dim3(256), 0, stream>>>(
      xb, wqb, Qb, Kb, Vout, nullptr);
  k_kvfused<<<dim3(4, 64), dim3(512), 0, stream>>>(Kb, Vout, projb, kvp, ksp);
  k_red<<<dim3(64, 4), dim3(256), 0, stream>>>(kvp, ksp, KVT, ksumf);
  k_numfused<<<dim3(4, 64), dim3(512), 0, stream>>>(Qb, projb, KVT, ksumf, merged);
  // out = merged @ Wo^T + bo -> f32 d_out (128*8 blocks, same swizzle)
  k_gemm_swz<1, 8><<<dim3(1024), dim3(256), 0, stream>>>(
      merged, wob, d_out, d_out, d_out, bo);
}

// Round 17
// 306.271 us; speedup vs baseline: 1.1739x; 1.1739x over previous
//
#include <hip/hip_runtime.h>

typedef unsigned short u16;
typedef __attribute__((ext_vector_type(8))) short s8v;       // 8 bf16 MFMA frag
typedef __attribute__((ext_vector_type(4))) float f4v;       // MFMA acc
typedef __attribute__((ext_vector_type(8))) unsigned short u16x8;
typedef __attribute__((ext_vector_type(4))) unsigned short u16x4;

__device__ __forceinline__ float b2f(u16 u) {
  unsigned int v = ((unsigned int)u) << 16;
  float f;
  __builtin_memcpy(&f, &v, 4);
  return f;
}
__device__ __forceinline__ u16 f2b(float f) {  // RNE f32 -> bf16
  unsigned int v;
  __builtin_memcpy(&v, &f, 4);
  v = v + 0x7fffu + ((v >> 16) & 1u);
  return (u16)(v >> 16);
}
__device__ __forceinline__ void gl_lds16(const void* g, void* l) {
  __builtin_amdgcn_global_load_lds((__attribute__((address_space(1))) void*)g,
                                   (__attribute__((address_space(3))) void*)l,
                                   16, 0, 0);
}
__device__ __forceinline__ f4v mfma16(s8v a, s8v b, f4v c) {
  return __builtin_amdgcn_mfma_f32_16x16x32_bf16(a, b, c, 0, 0, 0);
}

// ---------------- K0: f32 -> bf16 for x, Wq, Wk, Wv, Wo; proj pre-scaled 1/8
__global__ __launch_bounds__(256) void k_convert(
    const float* __restrict__ x, const float* __restrict__ wq,
    const float* __restrict__ wk, const float* __restrict__ wv,
    const float* __restrict__ wo, const float* __restrict__ proj,
    u16* __restrict__ xb, u16* __restrict__ wqb, u16* __restrict__ wkb,
    u16* __restrict__ wvb, u16* __restrict__ wob, u16* __restrict__ projb) {
  const int NX = 4194304, NW = 262144, NP = 65536;  // vec4 counts
  const int total = NX + 4 * NW + NP;
  for (int i = blockIdx.x * 256 + threadIdx.x; i < total; i += gridDim.x * 256) {
    const float* src;
    u16* dst;
    int off;
    float scale = 1.0f;
    if (i < NX) { src = x; dst = xb; off = i; }
    else if (i < NX + NW) { src = wq; dst = wqb; off = i - NX; }
    else if (i < NX + 2 * NW) { src = wk; dst = wkb; off = i - NX - NW; }
    else if (i < NX + 3 * NW) { src = wv; dst = wvb; off = i - NX - 2 * NW; }
    else if (i < NX + 4 * NW) { src = wo; dst = wob; off = i - NX - 3 * NW; }
    else { src = proj; dst = projb; off = i - NX - 4 * NW; scale = 0.125f; }
    const float4 v = reinterpret_cast<const float4*>(src)[off];
    u16x4 o;
    o[0] = f2b(v.x * scale); o[1] = f2b(v.y * scale);
    o[2] = f2b(v.z * scale); o[3] = f2b(v.w * scale);
    reinterpret_cast<u16x4*>(dst)[off] = o;
  }
}

// ---------------- pure-bf16 128x128 BT-GEMM, XCD-chunked flat grid.
// BK=64, chunk-XOR LDS swizzle; K fixed 1024. (r11, verified)
template <int COUTF32, int NCB>
__global__ __launch_bounds__(256) void k_gemm_swz(
    const u16* __restrict__ A, const u16* __restrict__ W,
    void* __restrict__ Cq, void* __restrict__ Ck, void* __restrict__ Cv,
    const float* __restrict__ bias) {
  const int bid = blockIdx.x;
  const int xcd = bid & 7, slot = bid >> 3;
  const int yg = slot / NCB, cb = slot - yg * NCB;
  const long row0 = (long)(yg * 8 + xcd) * 128;
  const int wrow0 = cb * 128;
  void* C = (cb < 8) ? Cq : (cb < 16) ? Ck : Cv;
  const int col0 = (cb & 7) * 128;
  __shared__ u16 As[128 * 64];
  __shared__ u16 Bs[128 * 64];
  const int tid = threadIdx.x, w = tid >> 6, l = tid & 63;
  const int wr = w >> 1, wc = w & 1, fr = l & 15, fq = l >> 4;
  f4v acc[4][4];
#pragma unroll
  for (int i = 0; i < 4; ++i)
#pragma unroll
    for (int j = 0; j < 4; ++j) acc[i][j] = 0.f;
  const int lr = l >> 3, lc = l & 7;  // staging: lane row-part / chunk
  for (int kt = 0; kt < 16; ++kt) {
    const int k0 = kt << 6;
    __syncthreads();  // prev compute done -> LDS rewrite safe
#pragma unroll
    for (int q = 0; q < 4; ++q) {
      const int r = q * 32 + w * 8 + lr;         // tile row this lane stages
      const int sc = (lc ^ (r & 7)) << 3;        // swizzled source chunk
      gl_lds16(A + (row0 + r) * 1024L + k0 + sc, (char*)As + q * 4096 + w * 1024);
      gl_lds16(W + (wrow0 + r) * 1024L + k0 + sc, (char*)Bs + q * 4096 + w * 1024);
    }
    __syncthreads();  // staged data visible
#pragma unroll
    for (int ks = 0; ks < 2; ++ks) {
      s8v af[4], bf[4];
#pragma unroll
      for (int i = 0; i < 4; ++i) {
        const int R = wr * 64 + i * 16 + fr;
        af[i] = *(const s8v*)&As[R * 64 + (((ks * 4 + fq) ^ (R & 7)) << 3)];
      }
#pragma unroll
      for (int j = 0; j < 4; ++j) {
        const int R = wc * 64 + j * 16 + fr;
        bf[j] = *(const s8v*)&Bs[R * 64 + (((ks * 4 + fq) ^ (R & 7)) << 3)];
      }
#pragma unroll
      for (int i = 0; i < 4; ++i)
#pragma unroll
        for (int j = 0; j < 4; ++j) acc[i][j] = mfma16(af[i], bf[j], acc[i][j]);
    }
  }
  if (COUTF32) {
#pragma unroll
    for (int j = 0; j < 4; ++j) {
      const int col = col0 + wc * 64 + j * 16 + fr;
      const float bv = bias ? bias[col] : 0.f;
#pragma unroll
      for (int i = 0; i < 4; ++i) {
        const long row = row0 + wr * 64 + i * 16 + fq * 4;
#pragma unroll
        for (int r = 0; r < 4; ++r)
          ((float*)C)[(row + r) * 1024L + col] = acc[i][j][r] + bv;
      }
    }
  } else {
    // per-wave LDS bounce -> vectorized 16B stores (full-line write segments)
    __syncthreads();  // all MFMA ds_reads of As/Bs done before reuse
    u16* myl = As + w * 1024;  // 2 KB per wave (16 x 64 u16)
    const int rr2 = l >> 2, c2 = (l & 3) * 16;
#pragma unroll
    for (int i = 0; i < 4; ++i) {
#pragma unroll
      for (int j = 0; j < 4; ++j)
#pragma unroll
        for (int r = 0; r < 4; ++r)
          myl[(fq * 4 + r) * 64 + j * 16 + fr] = f2b(acc[i][j][r]);
      // same-wave DS ops are ordered; lgkmcnt inserted by compiler before use
      const u16x8 o0 = *(const u16x8*)&myl[rr2 * 64 + c2];
      const u16x8 o1 = *(const u16x8*)&myl[rr2 * 64 + c2 + 8];
      u16* dst = (u16*)C + (row0 + wr * 64 + i * 16 + rr2) * 1024L + col0 + wc * 64 + c2;
      *(u16x8*)dst = o0;
      *(u16x8*)(dst + 8) = o1;
    }
  }
}

// ---------------- K2: fused phiK + split-K KV partials + f32 ksum ----------
// 8 waves, 128-t chunks, T14 async-stage, in-register norms (3 barriers/iter).
// grid (4 chunks of 1024 t, 64 bh).  (r13/r14, verified)
__global__ __launch_bounds__(512) void k_kvfused(
    const u16* __restrict__ Kb, const u16* __restrict__ Vb,
    const u16* __restrict__ projb, float* __restrict__ kvp,
    float* __restrict__ ksp) {
  __shared__ u16 Ps[256 * 72];     // proj head [m][dk]        36.0 KB
  __shared__ u16 PhiT[256 * 136];  // [m][t'+pad]              68.0 KB
  __shared__ u16 Ks[128 * 72];     // K subtile [t'][dk]       18.0 KB
  __shared__ u16 VT[64 * 136];     // V^T [e][t'+pad]          17.0 KB
  const int tid = threadIdx.x, w = tid >> 6, l = tid & 63;
  const int fr = l & 15, fq = l >> 4;
  const int c = blockIdx.x, bh = blockIdx.y, b = bh >> 4, h = bh & 15;
#pragma unroll
  for (int q = 0; q < 4; ++q) {
    const int flat = q * 4096 + tid * 8;
    const int m = flat >> 6, cc = flat & 63;
    *(u16x8*)&Ps[m * 72 + cc] = *(const u16x8*)&projb[h * 16384 + flat];
  }
  f4v kacc[2][4];
  float ksum = 0.f;
#pragma unroll
  for (int i = 0; i < 2; ++i)
#pragma unroll
    for (int j = 0; j < 4; ++j) kacc[i][j] = 0.f;
  // staging coords
  const int kr = tid >> 3, kc = (tid & 7) * 8;          // K: row-part, col
  const int vt = tid >> 2, ve0 = (tid & 3) * 16;        // V: t, e-base
  const long kbase = (long)b * 4096 + (long)c * 1024;
  // prologue: loads for it=0
  u16x8 ck0 = *(const u16x8*)&Kb[(kbase + kr) * 1024 + h * 64 + kc];
  u16x8 ck1 = *(const u16x8*)&Kb[(kbase + 64 + kr) * 1024 + h * 64 + kc];
  u16x8 cv0 = *(const u16x8*)&Vb[(kbase + vt) * 1024 + h * 64 + ve0];
  u16x8 cv1 = *(const u16x8*)&Vb[(kbase + vt) * 1024 + h * 64 + ve0 + 8];
  for (int it = 0; it < 8; ++it) {
    __syncthreads();  // A: prev iter's PhiT/VT/Ks reads done -> rewrite safe
    *(u16x8*)&Ks[kr * 72 + kc] = ck0;
    *(u16x8*)&Ks[(64 + kr) * 72 + kc] = ck1;
#pragma unroll
    for (int jj = 0; jj < 8; ++jj) VT[(ve0 + jj) * 136 + vt] = cv0[jj];
#pragma unroll
    for (int jj = 0; jj < 8; ++jj) VT[(ve0 + 8 + jj) * 136 + vt] = cv1[jj];
    __syncthreads();  // B: Ks / VT staged
    if (it < 7) {  // T14: issue next iter's loads under this iter's compute
      const long t0n = kbase + (it + 1) * 128;
      ck0 = *(const u16x8*)&Kb[(t0n + kr) * 1024 + h * 64 + kc];
      ck1 = *(const u16x8*)&Kb[(t0n + 64 + kr) * 1024 + h * 64 + kc];
      cv0 = *(const u16x8*)&Vb[(t0n + vt) * 1024 + h * 64 + ve0];
      cv1 = *(const u16x8*)&Vb[(t0n + vt) * 1024 + h * 64 + ve0 + 8];
    }
    float nrm;
    {  // in-register norms for row = w*16 + (l>>2) (intra-wave)
      const int row = w * 16 + (l >> 2), part = l & 3;
      const u16x8 a0 = *(const u16x8*)&Ks[row * 72 + part * 16];
      const u16x8 a1 = *(const u16x8*)&Ks[row * 72 + part * 16 + 8];
      float s = 0.f;
#pragma unroll
      for (int jj = 0; jj < 8; ++jj) { const float v = b2f(a0[jj]); s += v * v; }
#pragma unroll
      for (int jj = 0; jj < 8; ++jj) { const float v = b2f(a1[jj]); s += v * v; }
      s += __shfl_xor(s, 1);
      s += __shfl_xor(s, 2);
      nrm = s * 0.015625f;  // ||k/8||^2
    }
    f4v pacc[16];
#pragma unroll
    for (int f = 0; f < 16; ++f) pacc[f] = 0.f;
#pragma unroll
    for (int ks = 0; ks < 2; ++ks) {
      const s8v a = *(const s8v*)&Ks[(w * 16 + fr) * 72 + ks * 32 + fq * 8];
#pragma unroll
      for (int f = 0; f < 16; ++f) {
        const s8v bb = *(const s8v*)&Ps[(f * 16 + fr) * 72 + ks * 32 + fq * 8];
        pacc[f] = mfma16(a, bb, pacc[f]);
      }
    }
    float mx[4] = {-3.4e38f, -3.4e38f, -3.4e38f, -3.4e38f};
#pragma unroll
    for (int f = 0; f < 16; ++f)
#pragma unroll
      for (int r = 0; r < 4; ++r) mx[r] = fmaxf(mx[r], pacc[f][r]);
#pragma unroll
    for (int sft = 1; sft < 16; sft <<= 1)
#pragma unroll
      for (int r = 0; r < 4; ++r) mx[r] = fmaxf(mx[r], __shfl_xor(mx[r], sft));
    float nsq[4];
#pragma unroll
    for (int r = 0; r < 4; ++r) nsq[r] = __shfl(nrm, (fq * 4 + r) * 4);
#pragma unroll
    for (int f = 0; f < 16; ++f) {
      u16x4 o;
#pragma unroll
      for (int r = 0; r < 4; ++r)
        o[r] = f2b((__expf(pacc[f][r] - mx[r] - 0.5f * nsq[r]) + 1e-6f) * 0.0625f);
      *(u16x4*)&PhiT[(f * 16 + fr) * 136 + w * 16 + fq * 4] = o;
    }
    __syncthreads();  // D: PhiT visible (VT staged since B)
#pragma unroll
    for (int ks = 0; ks < 4; ++ks) {
      s8v af[2], bf[4];
#pragma unroll
      for (int i = 0; i < 2; ++i)
        af[i] = *(const s8v*)&PhiT[(w * 32 + i * 16 + fr) * 136 + ks * 32 + fq * 8];
#pragma unroll
      for (int j = 0; j < 4; ++j)
        bf[j] = *(const s8v*)&VT[(j * 16 + fr) * 136 + ks * 32 + fq * 8];
#pragma unroll
      for (int i = 0; i < 2; ++i)
#pragma unroll
        for (int j = 0; j < 4; ++j) kacc[i][j] = mfma16(af[i], bf[j], kacc[i][j]);
    }
    if (tid < 256) {  // f32 ksum: thread owns m = tid, sums 128 t's
#pragma unroll
      for (int t8 = 0; t8 < 16; ++t8) {
        const u16x8 p = *(const u16x8*)&PhiT[tid * 136 + t8 * 8];
#pragma unroll
        for (int jj = 0; jj < 8; ++jj) ksum += b2f(p[jj]);
      }
    }
  }
  const long obase = (long)(c * 64 + bh) * 16384;
#pragma unroll
  for (int i = 0; i < 2; ++i) {
    const int m = w * 32 + i * 16 + fq * 4;
#pragma unroll
    for (int j = 0; j < 4; ++j)
#pragma unroll
      for (int r = 0; r < 4; ++r)
        kvp[obase + (long)(m + r) * 64 + j * 16 + fr] = kacc[i][j][r];
  }
  if (tid < 256) ksp[(long)(c * 64 + bh) * 256 + tid] = ksum;
}

// ---------------- K3: reduce 4 split-K partials -> KVT bf16 [bh][e][m], f32 Ksum
__global__ __launch_bounds__(256) void k_red(
    const float* __restrict__ kvp, const float* __restrict__ ksp,
    u16* __restrict__ KVT, float* __restrict__ ksumf) {
  const int bh = blockIdx.x, qq = blockIdx.y, tid = threadIdx.x;
  for (int it = 0; it < 16; ++it) {
    const int idx = (qq * 16 + it) * 256 + tid;
    const int m = idx >> 6, e = idx & 63;
    float s = 0.f;
#pragma unroll
    for (int cc = 0; cc < 4; ++cc)
      s += kvp[(long)(cc * 64 + bh) * 16384 + (long)m * 64 + e];
    KVT[(long)bh * 16384 + (long)e * 256 + m] = f2b(s);
  }
  if (qq == 0) {
    float s = 0.f;
#pragma unroll
    for (int cc = 0; cc < 4; ++cc) s += ksp[(long)(cc * 64 + bh) * 256 + tid];
    ksumf[bh * 256 + tid] = s;
  }
}

// ---------------- K4: wave-independent fused phiQ + num + den -> merged -----
// (r14, verified best) 8 waves, ONE barrier; grid (4 t-quarters, 64 bh).
__global__ __launch_bounds__(512) void k_numfused(
    const u16* __restrict__ Qb, const u16* __restrict__ projb,
    const u16* __restrict__ KVT, const float* __restrict__ ksumf,
    u16* __restrict__ merged) {
  __shared__ u16 Ps[256 * 72];       // proj head           36.0 KB
  __shared__ u16 Bs[64 * 264];       // KVT[e][m+pad]       33.0 KB
  __shared__ u16 PhiW[8][16 * 264];  // per-wave scratch    67.6 KB
  __shared__ float ksl[256];
  const int tid = threadIdx.x, w = tid >> 6, l = tid & 63;
  const int fr = l & 15, fq = l >> 4;
  const int tq = blockIdx.x, bh = blockIdx.y, b = bh >> 4, h = bh & 15;
#pragma unroll
  for (int q = 0; q < 4; ++q) {
    const int flat = q * 4096 + tid * 8;
    *(u16x8*)&Ps[(flat >> 6) * 72 + (flat & 63)] =
        *(const u16x8*)&projb[h * 16384 + flat];
  }
  {
    const int e = tid >> 3, seg = (tid & 7) * 32;
#pragma unroll
    for (int k = 0; k < 4; ++k)
      *(u16x8*)&Bs[e * 264 + seg + k * 8] =
          *(const u16x8*)&KVT[(long)bh * 16384 + e * 256 + seg + k * 8];
  }
  if (tid < 256) ksl[tid] = ksumf[bh * 256 + tid];
  u16* Pw = &PhiW[w][0];
  const long tbase = (long)b * 4096 + tq * 1024 + w * 128;  // wave's t range
  const u16* qrow = Qb + (tbase + fr) * 1024 + h * 64 + fq * 8;
  s8v a0 = *(const s8v*)&qrow[0];
  s8v a1 = *(const s8v*)&qrow[32];
  __syncthreads();  // Ps / Bs / ksl staged (single barrier in kernel)
  for (int n = 0; n < 8; ++n) {
    s8v n0, n1;
    if (n < 7) {  // prefetch next tile's Q frags
      n0 = *(const s8v*)&qrow[(long)(n + 1) * 16 * 1024];
      n1 = *(const s8v*)&qrow[(long)(n + 1) * 16 * 1024 + 32];
    }
    // ||q/8||^2 for row fr of this tile (in-register, intra-wave)
    float s = 0.f;
#pragma unroll
    for (int jj = 0; jj < 8; ++jj) { const float v = b2f((u16)a0[jj]); s += v * v; }
#pragma unroll
    for (int jj = 0; jj < 8; ++jj) { const float v = b2f((u16)a1[jj]); s += v * v; }
    s += __shfl_xor(s, 16);
    s += __shfl_xor(s, 32);
    s *= 0.015625f;
    f4v pacc[16];
#pragma unroll
    for (int f = 0; f < 16; ++f) pacc[f] = 0.f;
#pragma unroll
    for (int f = 0; f < 16; ++f)
      pacc[f] = mfma16(a0, *(const s8v*)&Ps[(f * 16 + fr) * 72 + fq * 8], pacc[f]);
#pragma unroll
    for (int f = 0; f < 16; ++f)
      pacc[f] = mfma16(a1, *(const s8v*)&Ps[(f * 16 + fr) * 72 + 32 + fq * 8], pacc[f]);
    float mx[4] = {-3.4e38f, -3.4e38f, -3.4e38f, -3.4e38f};
#pragma unroll
    for (int f = 0; f < 16; ++f)
#pragma unroll
      for (int r = 0; r < 4; ++r) mx[r] = fmaxf(mx[r], pacc[f][r]);
#pragma unroll
    for (int sft = 1; sft < 16; sft <<= 1)
#pragma unroll
      for (int r = 0; r < 4; ++r) mx[r] = fmaxf(mx[r], __shfl_xor(mx[r], sft));
    float nsq[4];
#pragma unroll
    for (int r = 0; r < 4; ++r) nsq[r] = __shfl(s, fq * 4 + r);
    float dp[4] = {0.f, 0.f, 0.f, 0.f};
#pragma unroll
    for (int f = 0; f < 16; ++f) {
      const float kv = ksl[f * 16 + fr];
#pragma unroll
      for (int r = 0; r < 4; ++r) {
        const u16 pb = f2b((__expf(pacc[f][r] - mx[r] - 0.5f * nsq[r]) + 1e-6f) * 0.0625f);
        Pw[(fq * 4 + r) * 264 + f * 16 + fr] = pb;
        dp[r] += b2f(pb) * kv;  // den from the same bf16 phi as num
      }
    }
#pragma unroll
    for (int sft = 1; sft < 16; sft <<= 1)
#pragma unroll
      for (int r = 0; r < 4; ++r) dp[r] += __shfl_xor(dp[r], sft);
    float rd[4];
#pragma unroll
    for (int r = 0; r < 4; ++r) rd[r] = 1.0f / (dp[r] + 1e-6f);
    // num MFMA: A = Pw rows (t_local=fr), B = Bs (KVT[e][m])
    f4v acc[4];
#pragma unroll
    for (int j = 0; j < 4; ++j) acc[j] = 0.f;
#pragma unroll
    for (int kt = 0; kt < 8; ++kt) {
      const s8v af = *(const s8v*)&Pw[fr * 264 + kt * 32 + fq * 8];
#pragma unroll
      for (int j = 0; j < 4; ++j)
        acc[j] = mfma16(af, *(const s8v*)&Bs[(j * 16 + fr) * 264 + kt * 32 + fq * 8], acc[j]);
    }
    // bounce via Pw (phi dead after num MFMA; same-wave DS ordering)
#pragma unroll
    for (int j = 0; j < 4; ++j)
#pragma unroll
      for (int r = 0; r < 4; ++r)
        Pw[(fq * 4 + r) * 264 + j * 16 + fr] = f2b(acc[j][r] * rd[r]);
    {
      const u16x8 o0 = *(const u16x8*)&Pw[(l >> 2) * 264 + (l & 3) * 16];
      const u16x8 o1 = *(const u16x8*)&Pw[(l >> 2) * 264 + (l & 3) * 16 + 8];
      u16* dst = merged + (tbase + n * 16 + (l >> 2)) * 1024 + h * 64 + (l & 3) * 16;
      *(u16x8*)dst = o0;
      *(u16x8*)(dst + 8) = o1;
    }
    a0 = n0;
    a1 = n1;
  }
}

extern "C" void kernel_launch(void* const* d_in, const int* in_sizes, int n_in,
                              void* d_out, int out_size, void* d_ws, size_t ws_size,
                              hipStream_t stream) {
  const float* x = (const float*)d_in[0];
  const float* Wq = (const float*)d_in[1];
  const float* Wk = (const float*)d_in[2];
  const float* Wv = (const float*)d_in[3];
  const float* Wo = (const float*)d_in[4];
  const float* bo = (const float*)d_in[5];
  const float* proj = (const float*)d_in[6];
  char* ws = (char*)d_ws;
  // V (bf16) lives in the first 33.5 MB of d_out (f32, 67 MB) until the final
  // GEMM overwrites all of d_out with the f32 result.
  u16* Vout = (u16*)d_out;
  // workspace layout — peak ~111.7 MB
  u16* xb = (u16*)(ws + 0L);               // 33.5 MB; dead after QKV GEMM
  u16* wqb = (u16*)(ws + 33554432L);       // 2 MB  | wqb/wkb/wvb contiguous =
  u16* wkb = (u16*)(ws + 35651584L);       // 2 MB  | fused W [3072,1024]
  u16* wvb = (u16*)(ws + 37748736L);       // 2 MB  |
  u16* wob = (u16*)(ws + 39845888L);       // 2 MB; live until final GEMM
  u16* projb = (u16*)(ws + 41943040L);     // 0.5 MB
  u16* Qb = (u16*)(ws + 42467328L);        // 33.5 MB
  u16* Kb = (u16*)(ws + 76021760L);        // 33.5 MB; merged aliases after kvfused
  u16* KVT = (u16*)(ws + 109576192L);      // 2 MB
  float* ksumf = (float*)(ws + 111673344L);// 64 KB
  float* kvp = (float*)xb;                 // alias (xb dead): 16.8 MB
  float* ksp = (float*)(ws + 16777216L);   // alias inside xb: 0.25 MB
  u16* merged = Kb;                        // alias (Kb dead after kvfused)
  (void)in_sizes; (void)n_in; (void)out_size; (void)ws_size;

  k_convert<<<dim3(2048), dim3(256), 0, stream>>>(x, Wq, Wk, Wv, Wo, proj,
                                                  xb, wqb, wkb, wvb, wob, projb);
  // Q,K,V = x @ [Wq;Wk;Wv]^T  (fused W, XCD-chunked flat grid: 128*24 blocks)
  k_gemm_swz<0, 24><<<dim3(3072), dim3(256), 0, stream>>>(
      xb, wqb, Qb, Kb, Vout, nullptr);
  k_kvfused<<<dim3(4, 64), dim3(512), 0, stream>>>(Kb, Vout, projb, kvp, ksp);
  k_red<<<dim3(64, 4), dim3(256), 0, stream>>>(kvp, ksp, KVT, ksumf);
  k_numfused<<<dim3(4, 64), dim3(512), 0, stream>>>(Qb, projb, KVT, ksumf, merged);
  // out = merged @ Wo^T + bo -> f32 d_out (128*8 blocks, same swizzle)
  k_gemm_swz<1, 8><<<dim3(1024), dim3(256), 0, stream>>>(
      merged, wob, d_out, d_out, d_out, bo);
}